// Round 17
// baseline (321.850 us; speedup 1.0000x reference)
//
#include <hip/hip_runtime.h>
#include <hip/hip_bf16.h>

// Problem constants: T=512 tokens, D=2048 hidden, E=64 experts, K=8 top-k, F=768.
#define T_TOK 512
#define D_DIM 2048
#define E_NUM 64
#define K_TOP 8
#define F_DIM 768

typedef __bf16 bf16x8 __attribute__((ext_vector_type(8)));
typedef float  f32x4  __attribute__((ext_vector_type(4)));

#define AS1 __attribute__((address_space(1)))
#define AS3 __attribute__((address_space(3)))

// async global->LDS, 16B/lane; LDS dest = wave-uniform base + lane*16.
__device__ __forceinline__ void gll16(const void* g, void* l) {
    __builtin_amdgcn_global_load_lds((const AS1 uint32_t*)g, (AS3 uint32_t*)l, 16, 0, 0);
}

#define VM_WAIT_I(N) asm volatile("s_waitcnt vmcnt(" #N ")" ::: "memory")
#define VM_WAIT(N) VM_WAIT_I(N)

#define PIPE_STEP(WN, BUF, DOSTG, KN)            \
    do {                                          \
        VM_WAIT(WN);                              \
        __builtin_amdgcn_sched_barrier(0);        \
        __builtin_amdgcn_s_barrier();             \
        consume(BUF);                             \
        __builtin_amdgcn_s_barrier();             \
        __builtin_amdgcn_sched_barrier(0);        \
        if (DOSTG) stage(BUF, KN);                \
    } while (0)

// ---------------- workspace layout (bytes) ----------------
// cnt  : int[64]          @ 0
// ids  : int[64*512]      @ 4096
// pw   : float[4096]      @ 139264
// Xbf  : bf16[512*2048]   @ 155648   (2 MB)
// H    : bf16[4096*768]   @ 2252800  (6 MB)
// Y    : bf16[4096*2048]  @ 8544256  (16 MB)
#define WS_IDS   4096
#define WS_PW    139264
#define WS_XBF   155648
#define WS_H     2252800
#define WS_Y     8544256

__global__ void zero_cnt_kernel(int* __restrict__ cnt) {
    if (threadIdx.x < E_NUM) cnt[threadIdx.x] = 0;
}

// X fp32 -> bf16 pre-pass (separate kernel — measured faster than fusing
// into the router, which double-reads the x rows through the request pipe)
__global__ __launch_bounds__(256) void xcvt_kernel(
        const float* __restrict__ x, __bf16* __restrict__ xb) {
    const size_t i = ((size_t)blockIdx.x * 256 + threadIdx.x) * 8;
    const float4 a = *(const float4*)(x + i);
    const float4 b = *(const float4*)(x + i + 4);
    bf16x8 v;
    v[0]=(__bf16)a.x; v[1]=(__bf16)a.y; v[2]=(__bf16)a.z; v[3]=(__bf16)a.w;
    v[4]=(__bf16)b.x; v[5]=(__bf16)b.y; v[6]=(__bf16)b.z; v[7]=(__bf16)b.w;
    *(uint4*)(xb + i) = __builtin_bit_cast(uint4, v);
}

// ---------------- router: 2 tokens/block (256 blocks = 1/CU) ----------------
// Thread (c,e): quarter-dot for expert e over k-chunk c, for BOTH tokens —
// each gw dword is loaded once and used twice (gw requests 268 -> 134 MB).
__global__ __launch_bounds__(256) void router_kernel(
        const float* __restrict__ x, const float* __restrict__ gw,
        float* __restrict__ pair_w, int* __restrict__ cnt, int* __restrict__ ids) {
    const int t0  = blockIdx.x * 2;
    const int tid = threadIdx.x;
    const int e   = tid & 63;
    const int c   = tid >> 6;
    const float* xr0 = x + (size_t)t0 * D_DIM;
    const float* xr1 = xr0 + D_DIM;
    const int k0 = c * (D_DIM / 4);
    float s0 = 0.f, s1 = 0.f;
    #pragma unroll 8
    for (int k = 0; k < D_DIM / 4; k++) {
        const float wv = gw[(size_t)(k0 + k) * E_NUM + e];
        s0 += xr0[k0 + k] * wv;
        s1 += xr1[k0 + k] * wv;
    }
    __shared__ float part[2][4][64];
    part[0][c][e] = s0;
    part[1][c][e] = s1;
    __syncthreads();
    if (tid < 64) {  // first wave only; lane == e
        for (int t = 0; t < 2; t++) {
            float logit = part[t][0][e] + part[t][1][e] + part[t][2][e] + part[t][3][e];
            float cur = logit;
            float selV[8]; int selE[8];
            #pragma unroll
            for (int i = 0; i < 8; i++) {
                float bv = cur; int bi = e;
                #pragma unroll
                for (int off = 32; off > 0; off >>= 1) {
                    float ov = __shfl_xor(bv, off);
                    int   oi = __shfl_xor(bi, off);
                    if (ov > bv || (ov == bv && oi < bi)) { bv = ov; bi = oi; }
                }
                selV[i] = bv; selE[i] = bi;
                if (e == bi) cur = -INFINITY;
            }
            const float m = selV[0];
            float sum = 0.f;
            #pragma unroll
            for (int i = 0; i < 8; i++) sum += __expf(selV[i] - m);
            float myW = 0.f; int myE = 0;
            #pragma unroll
            for (int i = 0; i < 8; i++) {
                if (e == i) { myW = __expf(selV[i] - m) / sum; myE = selE[i]; }
            }
            if (e < 8) {
                pair_w[(t0 + t) * K_TOP + e] = myW;
                int pos = atomicAdd(&cnt[myE], 1);
                ids[myE * T_TOK + pos] = (t0 + t) * K_TOP + e;  // token = id>>3
            }
        }
    }
}

// ================= fused gate+up GEMM (R10 structure, verbatim) =========
// BM=128, BN=64, BK=32; per step A 8KB + Wg 8KB + Wu 8KB = 24KB / 6 gll.
// Ring-2 = 48 KB -> 3 blocks/CU; steady vmcnt(6) = one step in flight.
// XCD-bijective swizzle. Epilogue: H = silu(g)*u.
__global__ __launch_bounds__(256, 3) void gemm_gu_kernel(
        const __bf16* __restrict__ Abase, const float* __restrict__ B0w,
        const float* __restrict__ B1w, const int* __restrict__ cnt,
        const int* __restrict__ ids, __bf16* __restrict__ Out) {
    constexpr int NK  = 64;
    constexpr int NCT = F_DIM / 64;         // 12
    constexpr int CHK = NCT * E_NUM / 8;    // 96
    const int bid = blockIdx.y * NCT + blockIdx.x;
    const int wg  = (bid & 7) * CHK + (bid >> 3);   // XCD-contiguous experts
    const int e   = wg / NCT;
    const int ct  = wg % NCT;
    const int n = cnt[e];
    if (n <= 0) return;

    const int tid  = threadIdx.x;
    const int lane = tid & 63;
    const int w    = tid >> 6;
    const int g16  = lane >> 4;
    const int l16  = lane & 15;

    __shared__ __align__(16) char lds[2][24576];
    // buffer: A bf16 [chunk4][row128]x16B @0 | B0 f32 [k32][col64] @8192 | B1 @16384

    const float* b0 = B0w + (size_t)e * D_DIM * F_DIM
                    + (size_t)(tid >> 4) * F_DIM + ct * 64 + (tid & 15) * 4;
    const float* b1 = B1w + (size_t)e * D_DIM * F_DIM
                    + (size_t)(tid >> 4) * F_DIM + ct * 64 + (tid & 15) * 4;
    const int ach = tid >> 7;               // A chunks: ach, ach+2
    const int arw = tid & 127;
    const int ci  = w * 16 + l16;

    for (int mt = 0; mt * 128 < n; mt++) {
        const int ap  = mt * 128 + arw;
        const int aid = ids[(size_t)e * T_TOK + (ap < n ? ap : n - 1)];
        const __bf16* asrc = Abase + (size_t)(aid >> 3) * D_DIM;

        f32x4 acc0[8], acc1[8];
        #pragma unroll
        for (int m = 0; m < 8; m++) {
            acc0[m][0]=0.f; acc0[m][1]=0.f; acc0[m][2]=0.f; acc0[m][3]=0.f;
            acc1[m][0]=0.f; acc1[m][1]=0.f; acc1[m][2]=0.f; acc1[m][3]=0.f;
        }

        auto stage = [&](int buf, int ks) {   // exactly 6 gll per thread
            char* L = lds[buf];
            gll16(asrc + ks * 32 + ach * 8,            L + ach * 2048 + arw * 16);
            gll16(asrc + ks * 32 + (ach + 2) * 8,      L + (ach + 2) * 2048 + arw * 16);
            gll16(b0 + (size_t)(ks * 32) * F_DIM,      L + 8192 + tid * 16);
            gll16(b0 + (size_t)(ks * 32 + 16) * F_DIM, L + 12288 + tid * 16);
            gll16(b1 + (size_t)(ks * 32) * F_DIM,      L + 16384 + tid * 16);
            gll16(b1 + (size_t)(ks * 32 + 16) * F_DIM, L + 20480 + tid * 16);
        };
        auto consume = [&](int buf) {
            const char* L = lds[buf];
            const float* B0f = (const float*)(L + 8192);
            const float* B1f = (const float*)(L + 16384);
            bf16x8 bf0, bf1;
            #pragma unroll
            for (int i = 0; i < 8; i++) {
                bf0[i] = (__bf16)B0f[(g16 * 8 + i) * 64 + ci];
                bf1[i] = (__bf16)B1f[(g16 * 8 + i) * 64 + ci];
            }
            __builtin_amdgcn_s_setprio(1);
            #pragma unroll
            for (int m = 0; m < 8; m++) {
                bf16x8 af = __builtin_bit_cast(bf16x8,
                    *(const uint4*)(L + g16 * 2048 + (m * 16 + l16) * 16));
                acc0[m] = __builtin_amdgcn_mfma_f32_16x16x32_bf16(af, bf0, acc0[m], 0, 0, 0);
                acc1[m] = __builtin_amdgcn_mfma_f32_16x16x32_bf16(af, bf1, acc1[m], 0, 0, 0);
            }
            __builtin_amdgcn_s_setprio(0);
        };

        // prologue: fill ring (12 gll outstanding)
        stage(0, 0); stage(1, 1);

        for (int ks = 0; ks < NK - 2; ks++) {
            PIPE_STEP(6, ks & 1, true, ks + 2);
        }
        PIPE_STEP(6, NK & 1, false, 0);       // step NK-2
        PIPE_STEP(0, (NK - 1) & 1, false, 0); // step NK-1 (lds free for next mt)

        // epilogue: H = silu(g)*u
        #pragma unroll
        for (int m = 0; m < 8; m++) {
            #pragma unroll
            for (int r = 0; r < 4; r++) {
                const int p = mt * 128 + m * 16 + g16 * 4 + r;
                if (p < n) {
                    const int rid = ids[(size_t)e * T_TOK + p];
                    const float g = acc0[m][r], u = acc1[m][r];
                    const float hv = (g / (1.f + __expf(-g))) * u;
                    Out[(size_t)rid * F_DIM + ct * 64 + ci] = (__bf16)hv;
                }
            }
        }
    }
}

// ================= down GEMM, BN=256 (R14 structure, verbatim) =================
// BM=128, BN=256, BK=32; per step A 8KB + B 32KB = 40KB / 10 gll.
// Ring-2 = 80 KB -> exactly 2 blocks/CU; grid 8x64 = 512 = 2/CU balanced.
// A redundancy 8x (vs 16x at BN=128): down requested 603 -> 502 MB.
__global__ __launch_bounds__(256, 2) void gemm_down_kernel(
        const __bf16* __restrict__ Abase, const float* __restrict__ Bw,
        const int* __restrict__ cnt, const int* __restrict__ ids,
        __bf16* __restrict__ Out) {
    constexpr int NK  = 24;
    constexpr int NCT = D_DIM / 256;        // 8
    constexpr int CHK = NCT * E_NUM / 8;    // 64
    const int bid = blockIdx.y * NCT + blockIdx.x;
    const int wg  = (bid & 7) * CHK + (bid >> 3);
    const int e   = wg / NCT;
    const int ct  = wg % NCT;
    const int n = cnt[e];
    if (n <= 0) return;

    const int tid  = threadIdx.x;
    const int lane = tid & 63;
    const int w    = tid >> 6;
    const int g16  = lane >> 4;
    const int l16  = lane & 15;

    __shared__ __align__(16) char lds[2][40960];
    // buffer: A bf16 [chunk4][row128]x16B @0 (8KB) | B f32 [k32][col256] @8192 (32KB)

    // B staging: gll j stages k-rows j*4..j*4+3, 1KB contiguous per row
    const float* bsrc = Bw + (size_t)e * F_DIM * D_DIM
                      + (size_t)(tid >> 6) * D_DIM + ct * 256 + (tid & 63) * 4;
    const int ach = tid >> 7;
    const int arw = tid & 127;

    for (int mt = 0; mt * 128 < n; mt++) {
        __builtin_amdgcn_s_barrier();   // ring safe to re-stage (multi-mt only)
        const int ap  = mt * 128 + arw;
        const int aid = ids[(size_t)e * T_TOK + (ap < n ? ap : n - 1)];
        const __bf16* asrc = Abase + (size_t)aid * F_DIM;

        f32x4 acc[4][8];
        #pragma unroll
        for (int cg = 0; cg < 4; cg++)
            #pragma unroll
            for (int m = 0; m < 8; m++) {
                acc[cg][m][0]=0.f; acc[cg][m][1]=0.f;
                acc[cg][m][2]=0.f; acc[cg][m][3]=0.f;
            }

        auto stage = [&](int buf, int ks) {   // exactly 10 gll per thread
            char* L = lds[buf];
            gll16(asrc + ks * 32 + ach * 8,       L + ach * 2048 + arw * 16);
            gll16(asrc + ks * 32 + (ach + 2) * 8, L + (ach + 2) * 2048 + arw * 16);
            #pragma unroll
            for (int j = 0; j < 8; j++)
                gll16(bsrc + (size_t)(ks * 32 + j * 4) * D_DIM,
                      L + 8192 + j * 4096 + tid * 16);
        };
        auto consume = [&](int buf) {
            const char* L = lds[buf];
            const float* Bf = (const float*)(L + 8192);
            uint4 af[8];
            #pragma unroll
            for (int m = 0; m < 8; m++)
                af[m] = *(const uint4*)(L + g16 * 2048 + (m * 16 + l16) * 16);
            #pragma unroll
            for (int cg = 0; cg < 4; cg++) {
                bf16x8 bf;
                #pragma unroll
                for (int i = 0; i < 8; i++)
                    bf[i] = (__bf16)Bf[(g16 * 8 + i) * 256 + cg * 64 + w * 16 + l16];
                __builtin_amdgcn_s_setprio(1);
                #pragma unroll
                for (int m = 0; m < 8; m++)
                    acc[cg][m] = __builtin_amdgcn_mfma_f32_16x16x32_bf16(
                        __builtin_bit_cast(bf16x8, af[m]), bf, acc[cg][m], 0, 0, 0);
                __builtin_amdgcn_s_setprio(0);
            }
        };

        stage(0, 0); stage(1, 1);
        for (int ks = 0; ks < NK - 2; ks++) {
            PIPE_STEP(10, ks & 1, true, ks + 2);
        }
        PIPE_STEP(10, NK & 1, false, 0);
        PIPE_STEP(0, (NK - 1) & 1, false, 0);

        #pragma unroll
        for (int m = 0; m < 8; m++) {
            #pragma unroll
            for (int r = 0; r < 4; r++) {
                const int p = mt * 128 + m * 16 + g16 * 4 + r;
                if (p < n) {
                    const int rid = ids[(size_t)e * T_TOK + p];
                    const size_t base = (size_t)rid * D_DIM + ct * 256 + w * 16 + l16;
                    #pragma unroll
                    for (int cg = 0; cg < 4; cg++)
                        Out[base + cg * 64] = (__bf16)acc[cg][m][r];
                }
            }
        }
    }
}

// ---------------- combine: out[t] = sum_k w[t,k] * Y[t*8+k] ----------------
__global__ __launch_bounds__(256) void combine_kernel(
        const __bf16* __restrict__ Y, const float* __restrict__ pw,
        float* __restrict__ out) {
    const int t   = blockIdx.x;
    const int tid = threadIdx.x;
    const int d0  = tid * 8;
    float acc[8];
    #pragma unroll
    for (int j = 0; j < 8; j++) acc[j] = 0.f;
    #pragma unroll
    for (int k = 0; k < K_TOP; k++) {
        const float wgt = pw[t * K_TOP + k];
        bf16x8 v = *(const bf16x8*)(Y + (size_t)(t * K_TOP + k) * D_DIM + d0);
        #pragma unroll
        for (int j = 0; j < 8; j++) acc[j] += wgt * (float)v[j];
    }
    #pragma unroll
    for (int j = 0; j < 8; j++) out[(size_t)t * D_DIM + d0 + j] = acc[j];
}

extern "C" void kernel_launch(void* const* d_in, const int* in_sizes, int n_in,
                              void* d_out, int out_size, void* d_ws, size_t ws_size,
                              hipStream_t stream) {
    const float* x      = (const float*)d_in[0];
    const float* gw     = (const float*)d_in[1];
    const float* w_gate = (const float*)d_in[2];
    const float* w_up   = (const float*)d_in[3];
    const float* w_down = (const float*)d_in[4];
    float* out = (float*)d_out;

    char* ws = (char*)d_ws;
    int*    cnt = (int*)(ws);
    int*    ids = (int*)(ws + WS_IDS);
    float*  pw  = (float*)(ws + WS_PW);
    __bf16* xbf = (__bf16*)(ws + WS_XBF);
    __bf16* H   = (__bf16*)(ws + WS_H);
    __bf16* Y   = (__bf16*)(ws + WS_Y);

    zero_cnt_kernel<<<1, 64, 0, stream>>>(cnt);
    xcvt_kernel<<<T_TOK * D_DIM / (256 * 8), 256, 0, stream>>>(x, xbf);
    router_kernel<<<T_TOK / 2, 256, 0, stream>>>(x, gw, pw, cnt, ids);
    // fused gate+up: H = silu(X@Wg) * (X@Wu)   (768 blocks = 3/CU)
    gemm_gu_kernel<<<dim3(F_DIM / 64, E_NUM), 256, 0, stream>>>(
        xbf, w_gate, w_up, cnt, ids, H);
    // down: Y = H @ Wd  (512 blocks = 2/CU, BN=256)
    gemm_down_kernel<<<dim3(D_DIM / 256, E_NUM), 256, 0, stream>>>(
        H, w_down, cnt, ids, Y);
    combine_kernel<<<T_TOK, 256, 0, stream>>>(Y, pw, out);
}

// Round 18
// 303.042 us; speedup vs baseline: 1.0621x; 1.0621x over previous
//
#include <hip/hip_runtime.h>
#include <hip/hip_bf16.h>

// Problem constants: T=512 tokens, D=2048 hidden, E=64 experts, K=8 top-k, F=768.
#define T_TOK 512
#define D_DIM 2048
#define E_NUM 64
#define K_TOP 8
#define F_DIM 768

typedef __bf16 bf16x8 __attribute__((ext_vector_type(8)));
typedef float  f32x4  __attribute__((ext_vector_type(4)));

#define AS1 __attribute__((address_space(1)))
#define AS3 __attribute__((address_space(3)))

// async global->LDS, 16B/lane; LDS dest = wave-uniform base + lane*16.
__device__ __forceinline__ void gll16(const void* g, void* l) {
    __builtin_amdgcn_global_load_lds((const AS1 uint32_t*)g, (AS3 uint32_t*)l, 16, 0, 0);
}

#define VM_WAIT_I(N) asm volatile("s_waitcnt vmcnt(" #N ")" ::: "memory")
#define VM_WAIT(N) VM_WAIT_I(N)

#define PIPE_STEP(WN, BUF, DOSTG, KN)            \
    do {                                          \
        VM_WAIT(WN);                              \
        __builtin_amdgcn_sched_barrier(0);        \
        __builtin_amdgcn_s_barrier();             \
        consume(BUF);                             \
        __builtin_amdgcn_s_barrier();             \
        __builtin_amdgcn_sched_barrier(0);        \
        if (DOSTG) stage(BUF, KN);                \
    } while (0)

// ---------------- workspace layout (bytes) ----------------
// cnt  : int[64]          @ 0
// ids  : int[64*512]      @ 4096
// pw   : float[4096]      @ 139264
// Xbf  : bf16[512*2048]   @ 155648   (2 MB)
// H    : bf16[4096*768]   @ 2252800  (6 MB)
// Y    : bf16[4096*2048]  @ 8544256  (16 MB)
#define WS_IDS   4096
#define WS_PW    139264
#define WS_XBF   155648
#define WS_H     2252800
#define WS_Y     8544256

__global__ void zero_cnt_kernel(int* __restrict__ cnt) {
    if (threadIdx.x < E_NUM) cnt[threadIdx.x] = 0;
}

// X fp32 -> bf16 pre-pass (A-gather source for the fused pass)
__global__ __launch_bounds__(256) void xcvt_kernel(
        const float* __restrict__ x, __bf16* __restrict__ xb) {
    const size_t i = ((size_t)blockIdx.x * 256 + threadIdx.x) * 8;
    const float4 a = *(const float4*)(x + i);
    const float4 b = *(const float4*)(x + i + 4);
    bf16x8 v;
    v[0]=(__bf16)a.x; v[1]=(__bf16)a.y; v[2]=(__bf16)a.z; v[3]=(__bf16)a.w;
    v[4]=(__bf16)b.x; v[5]=(__bf16)b.y; v[6]=(__bf16)b.z; v[7]=(__bf16)b.w;
    *(uint4*)(xb + i) = __builtin_bit_cast(uint4, v);
}

// ---------------- router: logits -> softmax -> top-8 -> renorm ----------------
__global__ __launch_bounds__(256) void router_kernel(
        const float* __restrict__ x, const float* __restrict__ gw,
        float* __restrict__ pair_w, int* __restrict__ cnt, int* __restrict__ ids) {
    const int t   = blockIdx.x;
    const int tid = threadIdx.x;
    const int c   = tid >> 4;   // 16 k-chunks of 128
    const int g   = tid & 15;   // float4 expert group

    const float* xr  = x + (size_t)t * D_DIM + c * 128;
    const float4* gr = (const float4*)(gw + (size_t)(c * 128) * E_NUM + g * 4);

    f32x4 acc; acc[0]=0.f; acc[1]=0.f; acc[2]=0.f; acc[3]=0.f;
    #pragma unroll 8
    for (int k = 0; k < 128; k++) {
        const float xv = xr[k];
        const float4 wv = gr[(size_t)k * 16];
        acc[0] += xv * wv.x; acc[1] += xv * wv.y;
        acc[2] += xv * wv.z; acc[3] += xv * wv.w;
    }
    __shared__ f32x4 part[16][16];
    part[c][g] = acc;
    __syncthreads();
    if (tid < 64) {  // lane == e
        const int e = tid;
        float logit = 0.f;
        #pragma unroll
        for (int cc = 0; cc < 16; cc++) logit += part[cc][e >> 2][e & 3];
        float cur = logit;
        float selV[8]; int selE[8];
        #pragma unroll
        for (int i = 0; i < 8; i++) {
            float bv = cur; int bi = e;
            #pragma unroll
            for (int off = 32; off > 0; off >>= 1) {
                float ov = __shfl_xor(bv, off);
                int   oi = __shfl_xor(bi, off);
                if (ov > bv || (ov == bv && oi < bi)) { bv = ov; bi = oi; }
            }
            selV[i] = bv; selE[i] = bi;
            if (e == bi) cur = -INFINITY;
        }
        const float m = selV[0];
        float sum = 0.f;
        #pragma unroll
        for (int i = 0; i < 8; i++) sum += __expf(selV[i] - m);
        float myW = 0.f; int myE = 0;
        #pragma unroll
        for (int i = 0; i < 8; i++) {
            if (e == i) { myW = __expf(selV[i] - m) / sum; myE = selE[i]; }
        }
        if (e < 8) {
            pair_w[t * K_TOP + e] = myW;
            int pos = atomicAdd(&cnt[myE], 1);
            ids[myE * T_TOK + pos] = t * K_TOP + e;  // token = id>>3
        }
    }
}

// ================= dual-B-tile expert GEMM =================
// Per k-step (BK=32): stage A (8 KB, gathered rows) ONCE + TWO B 64-col
// tiles (8 KB each) = 24 KB / 6 gll per thread. Ring-2 = 48 KB LDS ->
// 3 blocks/CU; steady vmcnt(6) = one 24 KB step in flight per block.
// XCD-bijective swizzle: each XCD owns a contiguous run of experts.
// MODE 0 (gate+up fused): B0=Wg, B1=Wu, same 64-col tile; epilogue
//   H = silu(acc0) * acc1. A rows = tokens (id>>3), NCT = BSTR/64.
// MODE 1 (down): B0=B1=Wd, tiles ct*128 and ct*128+64; epilogue Y = acc.
//   A rows = pair ids, NCT = BSTR/128.
template<int NK, int BSTR, int MODE>
__global__ __launch_bounds__(256, 3) void gemm2_kernel(
        const __bf16* __restrict__ Abase, const float* __restrict__ B0w,
        const float* __restrict__ B1w, const int* __restrict__ cnt,
        const int* __restrict__ ids, __bf16* __restrict__ Out) {
    constexpr int NCT = (MODE == 0) ? (BSTR / 64) : (BSTR / 128);
    constexpr int NWG = NCT * E_NUM;
    constexpr int CHK = NWG / 8;
    const int bid = blockIdx.y * NCT + blockIdx.x;
    const int wg  = (bid & 7) * CHK + (bid >> 3);
    const int e   = wg / NCT;
    const int ct  = wg % NCT;
    const int n = cnt[e];
    if (n <= 0) return;

    const int tid  = threadIdx.x;
    const int lane = tid & 63;
    const int w    = tid >> 6;
    const int g16  = lane >> 4;
    const int l16  = lane & 15;

    __shared__ __align__(16) char lds[2][24576];
    // buffer: A bf16 [chunk4][row128]x16B @0 | B0 f32 [k32][col64] @8192 | B1 @16384

    const int bcol0 = (MODE == 0) ? ct * 64 : ct * 128;
    const int bcol1 = (MODE == 0) ? ct * 64 : ct * 128 + 64;
    const float* b0 = B0w + (size_t)e * NK * 32 * BSTR
                    + (size_t)(tid >> 4) * BSTR + bcol0 + (tid & 15) * 4;
    const float* b1 = B1w + (size_t)e * NK * 32 * BSTR
                    + (size_t)(tid >> 4) * BSTR + bcol1 + (tid & 15) * 4;
    const int ach = tid >> 7;               // A chunks: ach, ach+2
    const int arw = tid & 127;
    const int ci  = w * 16 + l16;

    for (int mt = 0; mt * 128 < n; mt++) {
        const int ap  = mt * 128 + arw;
        const int aid = ids[(size_t)e * T_TOK + (ap < n ? ap : n - 1)];
        const __bf16* asrc = Abase + (size_t)(MODE == 0 ? (aid >> 3) : aid)
                                   * (MODE == 0 ? D_DIM : F_DIM);

        f32x4 acc0[8], acc1[8];
        #pragma unroll
        for (int m = 0; m < 8; m++) {
            acc0[m][0]=0.f; acc0[m][1]=0.f; acc0[m][2]=0.f; acc0[m][3]=0.f;
            acc1[m][0]=0.f; acc1[m][1]=0.f; acc1[m][2]=0.f; acc1[m][3]=0.f;
        }

        auto stage = [&](int buf, int ks) {   // exactly 6 gll per thread
            char* L = lds[buf];
            gll16(asrc + ks * 32 + ach * 8,        L + ach * 2048 + arw * 16);
            gll16(asrc + ks * 32 + (ach + 2) * 8,  L + (ach + 2) * 2048 + arw * 16);
            gll16(b0 + (size_t)(ks * 32) * BSTR,      L + 8192 + tid * 16);
            gll16(b0 + (size_t)(ks * 32 + 16) * BSTR, L + 12288 + tid * 16);
            gll16(b1 + (size_t)(ks * 32) * BSTR,      L + 16384 + tid * 16);
            gll16(b1 + (size_t)(ks * 32 + 16) * BSTR, L + 20480 + tid * 16);
        };
        auto consume = [&](int buf) {
            const char* L = lds[buf];
            const float* B0f = (const float*)(L + 8192);
            const float* B1f = (const float*)(L + 16384);
            bf16x8 bf0, bf1;
            #pragma unroll
            for (int i = 0; i < 8; i++) {
                bf0[i] = (__bf16)B0f[(g16 * 8 + i) * 64 + ci];
                bf1[i] = (__bf16)B1f[(g16 * 8 + i) * 64 + ci];
            }
            __builtin_amdgcn_s_setprio(1);
            #pragma unroll
            for (int m = 0; m < 8; m++) {
                bf16x8 af = __builtin_bit_cast(bf16x8,
                    *(const uint4*)(L + g16 * 2048 + (m * 16 + l16) * 16));
                acc0[m] = __builtin_amdgcn_mfma_f32_16x16x32_bf16(af, bf0, acc0[m], 0, 0, 0);
                acc1[m] = __builtin_amdgcn_mfma_f32_16x16x32_bf16(af, bf1, acc1[m], 0, 0, 0);
            }
            __builtin_amdgcn_s_setprio(0);
        };

        // prologue: fill ring (12 gll outstanding)
        stage(0, 0); stage(1, 1);

        for (int ks = 0; ks < NK - 2; ks++) {
            PIPE_STEP(6, ks & 1, true, ks + 2);
        }
        PIPE_STEP(6, NK & 1, false, 0);       // step NK-2
        PIPE_STEP(0, (NK - 1) & 1, false, 0); // step NK-1

        // epilogue
        #pragma unroll
        for (int m = 0; m < 8; m++) {
            #pragma unroll
            for (int r = 0; r < 4; r++) {
                const int p = mt * 128 + m * 16 + g16 * 4 + r;
                if (p < n) {
                    const int rid = ids[(size_t)e * T_TOK + p];
                    if (MODE == 0) {
                        const float g = acc0[m][r], u = acc1[m][r];
                        const float hv = (g / (1.f + __expf(-g))) * u;
                        Out[(size_t)rid * F_DIM + ct * 64 + ci] = (__bf16)hv;
                    } else {
                        Out[(size_t)rid * D_DIM + ct * 128 + ci]      = (__bf16)acc0[m][r];
                        Out[(size_t)rid * D_DIM + ct * 128 + 64 + ci] = (__bf16)acc1[m][r];
                    }
                }
            }
        }
    }
}

// ---------------- combine: out[t] = sum_k w[t,k] * Y[t*8+k] ----------------
__global__ __launch_bounds__(256) void combine_kernel(
        const __bf16* __restrict__ Y, const float* __restrict__ pw,
        float* __restrict__ out) {
    const int t   = blockIdx.x;
    const int tid = threadIdx.x;
    const int d0  = tid * 8;
    float acc[8];
    #pragma unroll
    for (int j = 0; j < 8; j++) acc[j] = 0.f;
    #pragma unroll
    for (int k = 0; k < K_TOP; k++) {
        const float wgt = pw[t * K_TOP + k];
        bf16x8 v = *(const bf16x8*)(Y + (size_t)(t * K_TOP + k) * D_DIM + d0);
        #pragma unroll
        for (int j = 0; j < 8; j++) acc[j] += wgt * (float)v[j];
    }
    #pragma unroll
    for (int j = 0; j < 8; j++) out[(size_t)t * D_DIM + d0 + j] = acc[j];
}

extern "C" void kernel_launch(void* const* d_in, const int* in_sizes, int n_in,
                              void* d_out, int out_size, void* d_ws, size_t ws_size,
                              hipStream_t stream) {
    const float* x      = (const float*)d_in[0];
    const float* gw     = (const float*)d_in[1];
    const float* w_gate = (const float*)d_in[2];
    const float* w_up   = (const float*)d_in[3];
    const float* w_down = (const float*)d_in[4];
    float* out = (float*)d_out;

    char* ws = (char*)d_ws;
    int*    cnt = (int*)(ws);
    int*    ids = (int*)(ws + WS_IDS);
    float*  pw  = (float*)(ws + WS_PW);
    __bf16* xbf = (__bf16*)(ws + WS_XBF);
    __bf16* H   = (__bf16*)(ws + WS_H);
    __bf16* Y   = (__bf16*)(ws + WS_Y);

    zero_cnt_kernel<<<1, 64, 0, stream>>>(cnt);
    xcvt_kernel<<<T_TOK * D_DIM / (256 * 8), 256, 0, stream>>>(x, xbf);
    router_kernel<<<T_TOK, 256, 0, stream>>>(x, gw, pw, cnt, ids);
    // fused gate+up: H = silu(X@Wg) * (X@Wu)   (768 blocks = 3/CU)
    gemm2_kernel<64, F_DIM, 0><<<dim3(F_DIM / 64, E_NUM), 256, 0, stream>>>(
        xbf, w_gate, w_up, cnt, ids, H);
    // down: Y = H @ Wd  (BN=128: two Wd tiles share A, 1024 blocks = 3/CU capacity)
    gemm2_kernel<24, D_DIM, 1><<<dim3(D_DIM / 128, E_NUM), 256, 0, stream>>>(
        H, w_down, w_down, cnt, ids, Y);
    combine_kernel<<<T_TOK, 256, 0, stream>>>(Y, pw, out);
}